// Round 4
// baseline (275.446 us; speedup 1.0000x reference)
//
#include <hip/hip_runtime.h>

// SynthMorphLoss: soft-dice over int32 label maps + diffusion regularizer.
// B=1, D=160, H=192, W=224, 26 classes (class 0 ignored in dice mean).
// R4: single fused block-specialized kernel (diff blocks + hist blocks) to
// overlap the two HBM streams and drop per-kernel overhead. Diff waves own a
// 6-row slab and issue all 13 row-loads (52 data VGPRs) before consuming —
// R3's VGPR=28 proved the compiler collapsed the intended load batch.

namespace {
constexpr int NC    = 26;
constexpr int Dd    = 160, Hh = 192, Ww = 224;
constexpr int W4    = Ww / 4;               // 56 float4 per row
constexpr int NROWS = 3 * Dd * Hh;          // 92,160 rows
constexpr int N4L   = Dd * Hh * Ww / 4;     // 1,720,320 int4 per label map
// joint histogram: key = f*33 + m (stride 33 mixes both labels into banks)
constexpr int JSTRIDE = 33;
constexpr int NBINS   = NC * JSTRIDE;       // 858
constexpr int ROWS_PER_WAVE = 6;            // divides Hh -> slab stays in-plane
constexpr int DIFF_BLOCKS = NROWS / (ROWS_PER_WAVE * 4);   // 3840
constexpr int HIST_BLOCKS = 840;            // 840*256*8 == N4L exactly
constexpr int HT          = HIST_BLOCKS * 256;              // 215,040
}

__global__ void init_ws_kernel(unsigned int* __restrict__ joint,
                               double* __restrict__ sums) {
    int i = blockIdx.x * blockDim.x + threadIdx.x;
    if (i < NBINS) joint[i] = 0u;
    if (i < 3)     sums[i]  = 0.0;
}

__global__ __launch_bounds__(256) void fused_kernel(
        const int4*   __restrict__ f4,
        const int4*   __restrict__ m4,
        const float4* __restrict__ v4,
        unsigned int* __restrict__ gj,
        double*       __restrict__ gs) {
    __shared__ unsigned int hbins[NBINS];
    __shared__ float px[4], py[4], pz[4];
    const int lane = threadIdx.x & 63;
    const int wid  = threadIdx.x >> 6;

    if (blockIdx.x < DIFF_BLOCKS) {
        // ---------------- diffusion part ----------------
        const int gwave = (blockIdx.x * 256 + threadIdx.x) >> 6;
        const int r0    = gwave * ROWS_PER_WAVE;
        const int h0    = r0 % Hh;                 // multiple of 6
        const int d     = (r0 / Hh) % Dd;          // constant for the wave
        const bool al   = (lane < W4);
        const bool dzv  = (d < Dd - 1);            // wave-uniform
        const bool dy5  = (h0 != Hh - ROWS_PER_WAVE);  // row5 dy validity
        const float4 z4 = make_float4(0.f, 0.f, 0.f, 0.f);

        // issue all 13 row-loads before any consumption, interleaved so the
        // first consumer waits with many loads still outstanding
        const size_t b = (size_t)r0 * W4 + lane;
        const size_t zoff = (size_t)Hh * W4;
        float4 c0 = al ? v4[b]          : z4;
        float4 c1 = al ? v4[b + W4]     : z4;
        float4 q0 = (al && dzv) ? v4[b + zoff]          : z4;
        float4 c2 = al ? v4[b + 2 * W4] : z4;
        float4 q1 = (al && dzv) ? v4[b + zoff + W4]     : z4;
        float4 c3 = al ? v4[b + 3 * W4] : z4;
        float4 q2 = (al && dzv) ? v4[b + zoff + 2 * W4] : z4;
        float4 c4 = al ? v4[b + 4 * W4] : z4;
        float4 q3 = (al && dzv) ? v4[b + zoff + 3 * W4] : z4;
        float4 c5 = al ? v4[b + 5 * W4] : z4;
        float4 q4 = (al && dzv) ? v4[b + zoff + 4 * W4] : z4;
        const size_t b6 = (r0 + 6 < NROWS) ? (b + 6 * W4) : b;   // clamp last
        float4 c6 = al ? v4[b6]         : z4;
        float4 q5 = (al && dzv) ? v4[b + zoff + 5 * W4] : z4;

        float sx = 0.f, sy = 0.f, sz = 0.f;
#define ROW(A, B, Q, DYOK)                                                     \
        {                                                                      \
            float d1 = (A).y - (A).x, d2 = (A).z - (A).y, d3 = (A).w - (A).z;  \
            sx += d1 * d1 + d2 * d2 + d3 * d3;                                 \
            float nx = __shfl_down((A).x, 1);                                  \
            if (lane < W4 - 1) { float d4 = nx - (A).w; sx += d4 * d4; }       \
            if (DYOK) {                                                        \
                float e0 = (B).x - (A).x, e1 = (B).y - (A).y;                  \
                float e2 = (B).z - (A).z, e3 = (B).w - (A).w;                  \
                sy += e0 * e0 + e1 * e1 + e2 * e2 + e3 * e3;                   \
            }                                                                  \
            if (dzv) {                                                         \
                float e0 = (Q).x - (A).x, e1 = (Q).y - (A).y;                  \
                float e2 = (Q).z - (A).z, e3 = (Q).w - (A).w;                  \
                sz += e0 * e0 + e1 * e1 + e2 * e2 + e3 * e3;                   \
            }                                                                  \
        }
        ROW(c0, c1, q0, true)
        ROW(c1, c2, q1, true)
        ROW(c2, c3, q2, true)
        ROW(c3, c4, q3, true)
        ROW(c4, c5, q4, true)
        ROW(c5, c6, q5, dy5)
#undef ROW

        #pragma unroll
        for (int off = 32; off > 0; off >>= 1) {
            sx += __shfl_down(sx, off);
            sy += __shfl_down(sy, off);
            sz += __shfl_down(sz, off);
        }
        if (lane == 0) { px[wid] = sx; py[wid] = sy; pz[wid] = sz; }
        __syncthreads();
        if (threadIdx.x == 0) {
            atomicAdd(&gs[0], (double)(px[0] + px[1] + px[2] + px[3]));
            atomicAdd(&gs[1], (double)(py[0] + py[1] + py[2] + py[3]));
            atomicAdd(&gs[2], (double)(pz[0] + pz[1] + pz[2] + pz[3]));
        }
    } else {
        // ---------------- histogram part ----------------
        for (int i = threadIdx.x; i < NBINS; i += 256) hbins[i] = 0u;
        __syncthreads();

        const int g = (blockIdx.x - DIFF_BLOCKS) * 256 + threadIdx.x;
        int4 a0 = f4[g];
        int4 a1 = f4[g + HT];
        int4 a2 = f4[g + 2 * HT];
        int4 a3 = f4[g + 3 * HT];
        int4 a4 = f4[g + 4 * HT];
        int4 a5 = f4[g + 5 * HT];
        int4 a6 = f4[g + 6 * HT];
        int4 a7 = f4[g + 7 * HT];
        int4 b0 = m4[g];
        int4 b1 = m4[g + HT];
        int4 b2 = m4[g + 2 * HT];
        int4 b3 = m4[g + 3 * HT];
        int4 b4 = m4[g + 4 * HT];
        int4 b5 = m4[g + 5 * HT];
        int4 b6 = m4[g + 6 * HT];
        int4 b7 = m4[g + 7 * HT];

#define JACC(A, B)                                       \
        atomicAdd(&hbins[(A).x * JSTRIDE + (B).x], 1u);  \
        atomicAdd(&hbins[(A).y * JSTRIDE + (B).y], 1u);  \
        atomicAdd(&hbins[(A).z * JSTRIDE + (B).z], 1u);  \
        atomicAdd(&hbins[(A).w * JSTRIDE + (B).w], 1u);
        JACC(a0, b0) JACC(a1, b1) JACC(a2, b2) JACC(a3, b3)
        JACC(a4, b4) JACC(a5, b5) JACC(a6, b6) JACC(a7, b7)
#undef JACC

        __syncthreads();
        for (int i = threadIdx.x; i < NBINS; i += 256) {
            unsigned int v = hbins[i];
            if (v) atomicAdd(&gj[i], v);
        }
    }
}

__global__ void finalize_kernel(const unsigned int* __restrict__ gj,
                                const double* __restrict__ gs,
                                float* __restrict__ out) {
    int lane = threadIdx.x & 63;
    float term = 0.f;
    if (lane >= 1 && lane < NC) {
        float fv = 0.f, mv = 0.f;
        #pragma unroll
        for (int m = 0; m < NC; ++m) fv += (float)gj[lane * JSTRIDE + m];
        #pragma unroll
        for (int f = 0; f < NC; ++f) mv += (float)gj[f * JSTRIDE + lane];
        float iv = (float)gj[lane * JSTRIDE + lane];
        term = (2.f * iv + 1e-5f) / (fv + mv + 1e-5f);
    }
    #pragma unroll
    for (int off = 32; off > 0; off >>= 1) term += __shfl_down(term, off);
    if (threadIdx.x == 0 && blockIdx.x == 0) {
        float sim = 1.f - term * (1.f / 25.f);
        double mdx = gs[0] / ((double)3 * Dd * Hh * (Ww - 1));
        double mdy = gs[1] / ((double)3 * Dd * (Hh - 1) * Ww);
        double mdz = gs[2] / ((double)3 * (Dd - 1) * Hh * Ww);
        float smooth = (float)((mdx + mdy + mdz) / 3.0);
        out[0] = sim + smooth;
        out[1] = sim;
        out[2] = smooth;
    }
}

extern "C" void kernel_launch(void* const* d_in, const int* in_sizes, int n_in,
                              void* d_out, int out_size, void* d_ws, size_t ws_size,
                              hipStream_t stream) {
    const int*   fl = (const int*)d_in[0];
    const int*   ml = (const int*)d_in[1];
    const float* vf = (const float*)d_in[2];
    float* out = (float*)d_out;

    // workspace: [0, 3432) joint counts (858 uints); [3584, 3608) double sums[3]
    unsigned int* joint = (unsigned int*)d_ws;
    double*       sums  = (double*)((char*)d_ws + 3584);

    init_ws_kernel<<<1, 1024, 0, stream>>>(joint, sums);
    fused_kernel<<<DIFF_BLOCKS + HIST_BLOCKS, 256, 0, stream>>>(
        (const int4*)fl, (const int4*)ml, (const float4*)vf, joint, sums);
    finalize_kernel<<<1, 64, 0, stream>>>(joint, sums, out);
}